// Round 1
// baseline (80.206 us; speedup 1.0000x reference)
//
#include <hip/hip_runtime.h>
#include <math.h>

// Problem constants
#define BATCH 32
#define HHWW  12544          // 112*112
#define CH    96
#define CH4   24             // CH/4
#define CR    24             // reduced channels
#define NBLK  28             // pooling blocks per batch
#define ROWS_PER_BLK (HHWW / NBLK)   // 448
#define RDIM  16             // row-threads per block

// ---------------------------------------------------------------------------
// Kernel 1: per-block partial channel sums.
// grid = (BATCH, NBLK), block = (CH4, RDIM) = 384 threads.
// Thread (q, r) accumulates channel-quad q over rows {row0+r, row0+r+16, ...}.
// Coalescing: lanes sweep q fastest -> 24 consecutive float4 = 384B contiguous.
// ---------------------------------------------------------------------------
__global__ void se_pool_partial(const float* __restrict__ in,
                                float* __restrict__ partial) {
    const int b   = blockIdx.x;
    const int blk = blockIdx.y;
    const int q   = threadIdx.x;   // 0..23  channel quad
    const int r   = threadIdx.y;   // 0..15  row lane

    const float4* inb = (const float4*)(in) + (size_t)b * HHWW * CH4;

    float4 acc = make_float4(0.f, 0.f, 0.f, 0.f);
    const int row0 = blk * ROWS_PER_BLK;
    #pragma unroll 4
    for (int row = row0 + r; row < row0 + ROWS_PER_BLK; row += RDIM) {
        float4 v = inb[(size_t)row * CH4 + q];
        acc.x += v.x; acc.y += v.y; acc.z += v.z; acc.w += v.w;
    }

    __shared__ float4 sdata[RDIM][CH4];
    sdata[r][q] = acc;
    __syncthreads();

    if (r == 0) {
        float4 s = sdata[0][q];
        #pragma unroll
        for (int k = 1; k < RDIM; ++k) {
            float4 v = sdata[k][q];
            s.x += v.x; s.y += v.y; s.z += v.z; s.w += v.w;
        }
        ((float4*)partial)[((size_t)b * NBLK + blk) * CH4 + q] = s;
    }
}

// ---------------------------------------------------------------------------
// Kernel 2: finish pooling mean + squeeze (swish) + excite (sigmoid gate).
// grid = BATCH blocks, block = CH (96) threads.
// ---------------------------------------------------------------------------
__global__ void se_gate(const float* __restrict__ partial,
                        const float* __restrict__ w_reduce,  // [CH][CR]
                        const float* __restrict__ b_reduce,  // [CR]
                        const float* __restrict__ w_expand,  // [CR][CH]
                        const float* __restrict__ b_expand,  // [CH]
                        float* __restrict__ gate) {          // [BATCH][CH]
    const int b = blockIdx.x;
    const int c = threadIdx.x;   // 0..95

    __shared__ float pooled[CH];
    __shared__ float hsw[CR];

    float s = 0.f;
    #pragma unroll
    for (int k = 0; k < NBLK; ++k)
        s += partial[((size_t)b * NBLK + k) * CH + c];
    pooled[c] = s * (1.0f / (float)HHWW);
    __syncthreads();

    if (c < CR) {
        float h = b_reduce[c];
        #pragma unroll
        for (int i = 0; i < CH; ++i)
            h += pooled[i] * w_reduce[i * CR + c];
        float sg = 1.0f / (1.0f + expf(-h));
        hsw[c] = h * sg;   // swish
    }
    __syncthreads();

    float g = b_expand[c];
    #pragma unroll
    for (int j = 0; j < CR; ++j)
        g += hsw[j] * w_expand[j * CH + c];
    gate[(size_t)b * CH + c] = 1.0f / (1.0f + expf(-g));
}

// ---------------------------------------------------------------------------
// Kernel 3: out = in * gate[b][c], float4 grid-stride.
// ---------------------------------------------------------------------------
__global__ void se_scale(const float4* __restrict__ in,
                         const float4* __restrict__ gate4,   // [BATCH][CH4]
                         float4* __restrict__ out) {
    const int N4 = BATCH * HHWW * CH4;       // 9,633,792
    const int PB = HHWW * CH4;               // float4 per batch = 301,056
    const int stride = gridDim.x * blockDim.x;
    for (int i = blockIdx.x * blockDim.x + threadIdx.x; i < N4; i += stride) {
        int b = i / PB;
        int q = i % CH4;
        float4 g = gate4[b * CH4 + q];
        float4 v = in[i];
        float4 o = make_float4(v.x * g.x, v.y * g.y, v.z * g.z, v.w * g.w);
        out[i] = o;
    }
}

extern "C" void kernel_launch(void* const* d_in, const int* in_sizes, int n_in,
                              void* d_out, int out_size, void* d_ws, size_t ws_size,
                              hipStream_t stream) {
    const float* in       = (const float*)d_in[0];
    const float* w_reduce = (const float*)d_in[1];
    const float* b_reduce = (const float*)d_in[2];
    const float* w_expand = (const float*)d_in[3];
    const float* b_expand = (const float*)d_in[4];
    float* out = (float*)d_out;

    // workspace layout: partials [BATCH][NBLK][CH] floats, then gate [BATCH][CH]
    float* partial = (float*)d_ws;
    float* gate    = partial + (size_t)BATCH * NBLK * CH;   // offset 344,064 B (16B aligned)

    dim3 gridA(BATCH, NBLK);
    dim3 blockA(CH4, RDIM);
    se_pool_partial<<<gridA, blockA, 0, stream>>>(in, partial);

    se_gate<<<BATCH, CH, 0, stream>>>(partial, w_reduce, b_reduce,
                                      w_expand, b_expand, gate);

    se_scale<<<2048, 256, 0, stream>>>((const float4*)in, (const float4*)gate, (float4*)out);
}

// Round 2
// 73.219 us; speedup vs baseline: 1.0954x; 1.0954x over previous
//
#include <hip/hip_runtime.h>
#include <math.h>

// Problem constants
#define BATCH 32
#define HHWW  12544          // 112*112
#define CH    96
#define CH4   24             // CH/4
#define CR    24             // reduced channels
#define NBLK  28             // pooling blocks per batch
#define ROWS_PER_BLK (HHWW / NBLK)   // 448
#define RDIM  16             // row-threads per block

typedef float f32x4 __attribute__((ext_vector_type(4)));

// ---------------------------------------------------------------------------
// Kernel 1: per-block partial channel sums.
// grid = (BATCH, NBLK), block = (CH4, RDIM) = 384 threads.
// Normal (caching) loads on purpose: leaves the input resident in L3 for the
// scale pass.
// ---------------------------------------------------------------------------
__global__ void se_pool_partial(const float* __restrict__ in,
                                float* __restrict__ partial) {
    const int b   = blockIdx.x;
    const int blk = blockIdx.y;
    const int q   = threadIdx.x;   // 0..23  channel quad
    const int r   = threadIdx.y;   // 0..15  row lane

    const f32x4* inb = (const f32x4*)(in) + (size_t)b * HHWW * CH4;

    f32x4 acc = (f32x4)(0.f);
    const int row0 = blk * ROWS_PER_BLK;
    #pragma unroll 4
    for (int row = row0 + r; row < row0 + ROWS_PER_BLK; row += RDIM) {
        acc += inb[(size_t)row * CH4 + q];
    }

    __shared__ f32x4 sdata[RDIM][CH4];
    sdata[r][q] = acc;
    __syncthreads();

    if (r == 0) {
        f32x4 s = sdata[0][q];
        #pragma unroll
        for (int k = 1; k < RDIM; ++k) s += sdata[k][q];
        ((f32x4*)partial)[((size_t)b * NBLK + blk) * CH4 + q] = s;
    }
}

// ---------------------------------------------------------------------------
// Kernel 2: finish pooling mean + squeeze (swish) + excite (sigmoid gate).
// grid = BATCH blocks, block = CH (96) threads.
// ---------------------------------------------------------------------------
__global__ void se_gate(const float* __restrict__ partial,
                        const float* __restrict__ w_reduce,  // [CH][CR]
                        const float* __restrict__ b_reduce,  // [CR]
                        const float* __restrict__ w_expand,  // [CR][CH]
                        const float* __restrict__ b_expand,  // [CH]
                        float* __restrict__ gate) {          // [BATCH][CH]
    const int b = blockIdx.x;
    const int c = threadIdx.x;   // 0..95

    __shared__ float pooled[CH];
    __shared__ float hsw[CR];

    float s = 0.f;
    #pragma unroll
    for (int k = 0; k < NBLK; ++k)
        s += partial[((size_t)b * NBLK + k) * CH + c];
    pooled[c] = s * (1.0f / (float)HHWW);
    __syncthreads();

    if (c < CR) {
        float h = b_reduce[c];
        #pragma unroll
        for (int i = 0; i < CH; ++i)
            h += pooled[i] * w_reduce[i * CR + c];
        float sg = 1.0f / (1.0f + expf(-h));
        hsw[c] = h * sg;   // swish
    }
    __syncthreads();

    float g = b_expand[c];
    #pragma unroll
    for (int j = 0; j < CR; ++j)
        g += hsw[j] * w_expand[j * CH + c];
    gate[(size_t)b * CH + c] = 1.0f / (1.0f + expf(-g));
}

// ---------------------------------------------------------------------------
// Kernel 3: out = in * gate[b][c].
// grid = (HHWW*CH4/256, BATCH) = (1176, 32), block 256, one float4/thread.
// Input read: normal load -> hits L3 (populated by pool pass).
// Output: NON-TEMPORAL store -> does not evict the input from L3.
// ---------------------------------------------------------------------------
__global__ void __launch_bounds__(256)
se_scale(const f32x4* __restrict__ in,
         const f32x4* __restrict__ gate4,   // [BATCH][CH4]
         f32x4* __restrict__ out) {
    const int b   = blockIdx.y;
    const int idx = blockIdx.x * 256 + threadIdx.x;   // 0 .. 301055
    const int q   = idx % CH4;

    const f32x4 g = gate4[b * CH4 + q];
    const size_t off = (size_t)b * (HHWW * CH4) + idx;
    f32x4 v = in[off];
    __builtin_nontemporal_store(v * g, &out[off]);
}

extern "C" void kernel_launch(void* const* d_in, const int* in_sizes, int n_in,
                              void* d_out, int out_size, void* d_ws, size_t ws_size,
                              hipStream_t stream) {
    const float* in       = (const float*)d_in[0];
    const float* w_reduce = (const float*)d_in[1];
    const float* b_reduce = (const float*)d_in[2];
    const float* w_expand = (const float*)d_in[3];
    const float* b_expand = (const float*)d_in[4];
    float* out = (float*)d_out;

    // workspace layout: partials [BATCH][NBLK][CH] floats, then gate [BATCH][CH]
    float* partial = (float*)d_ws;
    float* gate    = partial + (size_t)BATCH * NBLK * CH;   // 16B-aligned offset

    dim3 gridA(BATCH, NBLK);
    dim3 blockA(CH4, RDIM);
    se_pool_partial<<<gridA, blockA, 0, stream>>>(in, partial);

    se_gate<<<BATCH, CH, 0, stream>>>(partial, w_reduce, b_reduce,
                                      w_expand, b_expand, gate);

    dim3 gridC(HHWW * CH4 / 256, BATCH);
    se_scale<<<gridC, 256, 0, stream>>>((const f32x4*)in, (const f32x4*)gate, (f32x4*)out);
}